// Round 1
// baseline (457.138 us; speedup 1.0000x reference)
//
#include <hip/hip_runtime.h>
#include <stdint.h>

#define NM 128   // matrix dim / electrons
#define NT 512   // 8 waves; wave w owns ONE group of 16 cols: 16w..16w+15.
                 // lane l owns rows l, l+64.
                 // 8 rounds total (bootstrap + 7), vs 16 in the chunked scheme.

typedef float v2f __attribute__((ext_vector_type(2)));

__device__ __forceinline__ float readlane_f(float v, int lane) {
    return __int_as_float(__builtin_amdgcn_readlane(__float_as_int(v), lane));
}

// Full 64-lane unsigned max via DPP (VALU pipe); result valid in lane 63.
__device__ __forceinline__ unsigned wave_max_dpp(unsigned x) {
    int v = (int)x;
#define DPP_STEP(ctrl) \
    { int o = __builtin_amdgcn_update_dpp(0, v, ctrl, 0xf, 0xf, true); \
      v = ((unsigned)o > (unsigned)v) ? o : v; }
    DPP_STEP(0x111)  // row_shr:1
    DPP_STEP(0x112)  // row_shr:2
    DPP_STEP(0x114)  // row_shr:4
    DPP_STEP(0x118)  // row_shr:8
    DPP_STEP(0x142)  // row_bcast:15
    DPP_STEP(0x143)  // row_bcast:31
#undef DPP_STEP
    return (unsigned)v;
}

__device__ __forceinline__ unsigned pack_key(float v, int r) {
    // monotone in |v|; drop 6 mantissa LSBs to make room for the 7-bit row id
    return (((__float_as_uint(v) & 0x7fffffffu) >> 6) << 7) | (unsigned)r;
}

// max(ka,kb) over the wave, broadcast to all lanes (uniform result)
__device__ __forceinline__ unsigned argmax_bcast(unsigned ka, unsigned kb) {
    const unsigned m = wave_max_dpp(ka > kb ? ka : kb);
    return (unsigned)__builtin_amdgcn_readlane((int)m, 63);
}

// read pivot row p's element of a (row r0, row r1) register pair; p uniform
__device__ __forceinline__ float sel_readlane(v2f c, int p) {
    return (p < 64) ? readlane_f(c.x, p) : readlane_f(c.y, p - 64);
}

// Factor this wave's 16 columns (group g) in place; publish pre-multiplied,
// pre-zeroed multipliers to colvg, pivot keys + exact pivots, and the
// per-group new-pivot-row ballots. Inner extractions batched per pivot:
// one uniform branch, then contiguous readlanes, then contiguous pk_fma.
__device__ __forceinline__ void factor16(v2f (&sv)[16], bool& elim0, bool& elim1,
                                         int r0, int r1, int l, int g,
                                         float2 (*colvg)[64],
                                         unsigned* keysF, float* pivsF,
                                         ulonglong2* masks) {
    const bool e0in = elim0, e1in = elim1;
#pragma unroll
    for (int i = 0; i < 16; ++i) {
        const v2f c = sv[i];
        const unsigned key = argmax_bcast(elim0 ? 0u : pack_key(c.x, r0),
                                          elim1 ? 0u : pack_key(c.y, r1));
        const int pu = __builtin_amdgcn_readfirstlane((int)(key & 127u));
        const float piv = sel_readlane(c, pu);
        const float rcp = __builtin_amdgcn_rcpf(piv);
        elim0 = elim0 || (r0 == pu);
        elim1 = elim1 || (r1 == pu);
        const v2f lm = { elim0 ? 0.0f : c.x * rcp,
                         elim1 ? 0.0f : c.y * rcp };
        colvg[i][l] = make_float2(lm.x, lm.y);
        float u[16];
        if (pu < 64) {
#pragma unroll
            for (int m = i + 1; m < 16; ++m) u[m] = readlane_f(sv[m].x, pu);
        } else {
#pragma unroll
            for (int m = i + 1; m < 16; ++m) u[m] = readlane_f(sv[m].y, pu - 64);
        }
#pragma unroll
        for (int m = i + 1; m < 16; ++m)
            sv[m] = __builtin_elementwise_fma((v2f){-u[m], -u[m]}, lm, sv[m]);
        if (l == 0) { keysF[16 * g + i] = key; pivsF[16 * g + i] = piv; }
    }
    const unsigned long long b0 = __ballot(elim0 && !e0in);
    const unsigned long long b1 = __ballot(elim1 && !e1in);
    if (l == 0) masks[g] = make_ulonglong2(b0, b1);
}

// Apply pivots [I0, I0+8) of the current round to all 16 of this wave's
// columns. colv reads hoisted up front (one lgkm wait for 8 ds_read_b64);
// per pivot: 16 independent readlanes then 16 pk_fma (16-wide ILP).
template<int I0>
__device__ __forceinline__ void apply8x16(v2f (&sv)[16],
                                          const unsigned* keysR,
                                          const float2 (*colvp)[64], int l) {
    float2 la[8];
#pragma unroll
    for (int i = 0; i < 8; ++i) la[i] = colvp[I0 + i][l];
    const uint4 ka = *(const uint4*)&keysR[I0];
    const uint4 kb = *(const uint4*)&keysR[I0 + 4];
    int p[8];
    p[0] = __builtin_amdgcn_readfirstlane((int)(ka.x & 127u));
    p[1] = __builtin_amdgcn_readfirstlane((int)(ka.y & 127u));
    p[2] = __builtin_amdgcn_readfirstlane((int)(ka.z & 127u));
    p[3] = __builtin_amdgcn_readfirstlane((int)(ka.w & 127u));
    p[4] = __builtin_amdgcn_readfirstlane((int)(kb.x & 127u));
    p[5] = __builtin_amdgcn_readfirstlane((int)(kb.y & 127u));
    p[6] = __builtin_amdgcn_readfirstlane((int)(kb.z & 127u));
    p[7] = __builtin_amdgcn_readfirstlane((int)(kb.w & 127u));
#pragma unroll
    for (int i = 0; i < 8; ++i) {
        const v2f lm = (v2f){la[i].x, la[i].y};
        float u[16];
        if (p[i] < 64) {
#pragma unroll
            for (int j = 0; j < 16; ++j) u[j] = readlane_f(sv[j].x, p[i]);
        } else {
#pragma unroll
            for (int j = 0; j < 16; ++j) u[j] = readlane_f(sv[j].y, p[i] - 64);
        }
#pragma unroll
        for (int j = 0; j < 16; ++j)
            sv[j] = __builtin_elementwise_fma((v2f){-u[j], -u[j]}, lm, sv[j]);
    }
}

__global__ __launch_bounds__(NT, 8)   // 8 waves/EU = 4 blocks/CU
void slater_logdet(const float* __restrict__ rs,
                   const float* __restrict__ kpts,
                   const float* __restrict__ csw,
                   const float* __restrict__ ssw,
                   float* __restrict__ out) {
    __shared__ float2 colv[2][16][64];     // double-buffered multiplier panels
    __shared__ unsigned keysF[NM];         // write-once pivot keys per step
    __shared__ float    pivsF[NM];         // write-once exact pivots
    __shared__ ulonglong2 masks[NM / 16];  // per-group new-pivot row ballots
    __shared__ float    redf[2];

    const int t  = threadIdx.x;
    const int b  = blockIdx.x;
    const int w  = t >> 6;    // wave id; owns cols 16w..16w+15
    const int l  = t & 63;
    const int r0 = l, r1 = l + 64;

    v2f sv[16];   // sv[j] = (rows r0,r1) at col 16w+j
    {
        const float x0 = rs[(b * NM + r0) * 3 + 0];
        const float y0 = rs[(b * NM + r0) * 3 + 1];
        const float z0 = rs[(b * NM + r0) * 3 + 2];
        const float x1 = rs[(b * NM + r1) * 3 + 0];
        const float y1 = rs[(b * NM + r1) * 3 + 1];
        const float z1 = rs[(b * NM + r1) * 3 + 2];
#pragma unroll
        for (int j = 0; j < 16; ++j) {
            const int m = 16 * w + j;
            const float kx = kpts[m * 3 + 0], ky = kpts[m * 3 + 1], kz = kpts[m * 3 + 2];
            const float cw = csw[m], sw = ssw[m];
            float sn, cn;
            __sincosf(kx * x0 + ky * y0 + kz * z0, &sn, &cn);
            sv[j].x = cw * cn - sw * sn;
            __sincosf(kx * x1 + ky * y1 + kz * z1, &sn, &cn);
            sv[j].y = cw * cn - sw * sn;
        }
    }

    bool elim0 = false, elim1 = false;

    // ---- bootstrap: wave 0 factors & publishes group 0 ----
    if (w == 0)
        factor16(sv, elim0, elim1, r0, r1, l, 0, colv[0], keysF, pivsF, masks);
    __syncthreads();

    // ---- main loop: 7 rounds; round rd applies group rd (waves w > rd),
    //      then wave rd+1 factors group rd+1 into the other colv buffer.
    //      Pivot order and per-column update order are identical to the
    //      chunked scheme -> numerically identical result.
    for (int rd = 0; rd < 7; ++rd) {
        if (w > rd) {
            const ulonglong2 mk = masks[rd];
            elim0 = elim0 || (((mk.x >> l) & 1ull) != 0);
            elim1 = elim1 || (((mk.y >> l) & 1ull) != 0);
            const unsigned* keysR = &keysF[16 * rd];
            const float2 (*cp)[64] = colv[rd & 1];
            apply8x16<0>(sv, keysR, cp, l);
            apply8x16<8>(sv, keysR, cp, l);
            if (w == rd + 1)
                factor16(sv, elim0, elim1, r0, r1, l, rd + 1,
                         colv[(rd + 1) & 1], keysF, pivsF, masks);
        }
        __syncthreads();
    }

    // ---- log|det| = sum log|piv_k| over the write-once pivsF array ----
    float lg = 0.0f;
    if (t < NM) {
        lg = __logf(fabsf(pivsF[t]));
#pragma unroll
        for (int off = 32; off > 0; off >>= 1)
            lg += __shfl_xor(lg, off, 64);
        if ((t & 63) == 0) redf[t >> 6] = lg;
    }
    __syncthreads();
    if (t == 0) out[b] = redf[0] + redf[1];
}

extern "C" void kernel_launch(void* const* d_in, const int* in_sizes, int n_in,
                              void* d_out, int out_size, void* d_ws, size_t ws_size,
                              hipStream_t stream) {
    const float* rs = (const float*)d_in[0];
    const float* kp = (const float*)d_in[1];
    const float* cs = (const float*)d_in[2];
    const float* ss = (const float*)d_in[3];
    float* out = (float*)d_out;
    const int batch = in_sizes[0] / (NM * 3);  // 4096
    slater_logdet<<<dim3(batch), dim3(NT), 0, stream>>>(rs, kp, cs, ss, out);
}

// Round 2
// 423.417 us; speedup vs baseline: 1.0796x; 1.0796x over previous
//
#include <hip/hip_runtime.h>
#include <stdint.h>

#define NM 128   // matrix dim / electrons
#define NT 512   // 8 waves; BALANCED pairing: wave w owns group w (cols 8w..8w+7)
                 // in sv[0..7] and group 15-w (cols 8*(15-w)..) in sv[8..15].
                 // Every wave: exactly 1016 apply pairs (was 568..1464 with w,w+8).
                 // lane l owns rows l, l+64. 16 rounds of 8 pivots (R0 schedule).

typedef float v2f __attribute__((ext_vector_type(2)));

__device__ __forceinline__ float readlane_f(float v, int lane) {
    return __int_as_float(__builtin_amdgcn_readlane(__float_as_int(v), lane));
}

// Full 64-lane unsigned max via DPP (VALU pipe); result valid in lane 63.
__device__ __forceinline__ unsigned wave_max_dpp(unsigned x) {
    int v = (int)x;
#define DPP_STEP(ctrl) \
    { int o = __builtin_amdgcn_update_dpp(0, v, ctrl, 0xf, 0xf, true); \
      v = ((unsigned)o > (unsigned)v) ? o : v; }
    DPP_STEP(0x111)  // row_shr:1
    DPP_STEP(0x112)  // row_shr:2
    DPP_STEP(0x114)  // row_shr:4
    DPP_STEP(0x118)  // row_shr:8
    DPP_STEP(0x142)  // row_bcast:15
    DPP_STEP(0x143)  // row_bcast:31
#undef DPP_STEP
    return (unsigned)v;
}

__device__ __forceinline__ unsigned pack_key(float v, int r) {
    // monotone in |v|; drop 6 mantissa LSBs to make room for the 7-bit row id
    return (((__float_as_uint(v) & 0x7fffffffu) >> 6) << 7) | (unsigned)r;
}

// max(ka,kb) over the wave, broadcast to all lanes (uniform result)
__device__ __forceinline__ unsigned argmax_bcast(unsigned ka, unsigned kb) {
    const unsigned m = wave_max_dpp(ka > kb ? ka : kb);
    return (unsigned)__builtin_amdgcn_readlane((int)m, 63);
}

// read pivot row p's element of a (row r0, row r1) register pair; p uniform
__device__ __forceinline__ float sel_readlane(v2f c, int p) {
    return (p < 64) ? readlane_f(c.x, p) : readlane_f(c.y, p - 64);
}

// factor 8 cols sv[B..B+7] in place, publishing pre-multiplied + pre-zeroed
// multipliers, keys, exact pivots, elim ballots. Inner extractions batched:
// one uniform branch per pivot, then contiguous readlanes, then pk_fma.
template<int B>
__device__ __forceinline__ void lookahead8(v2f (&sv)[16], bool& elim0, bool& elim1,
                                           int r0, int r1, int l, int g,
                                           float2 (*colvg)[64],
                                           unsigned* keysF, float* pivsF,
                                           ulonglong2* masks) {
    const bool e0in = elim0, e1in = elim1;
    __builtin_amdgcn_s_setprio(1);   // convoy-critical wave: favor its issue
#pragma unroll
    for (int i = 0; i < 8; ++i) {
        const v2f c = sv[B + i];
        const unsigned key = argmax_bcast(elim0 ? 0u : pack_key(c.x, r0),
                                          elim1 ? 0u : pack_key(c.y, r1));
        const int pu = __builtin_amdgcn_readfirstlane((int)(key & 127u));
        const float piv = sel_readlane(c, pu);
        const float rcp = __builtin_amdgcn_rcpf(piv);
        elim0 = elim0 || (r0 == pu);
        elim1 = elim1 || (r1 == pu);
        const v2f lm = { elim0 ? 0.0f : c.x * rcp,
                         elim1 ? 0.0f : c.y * rcp };
        colvg[i][l] = make_float2(lm.x, lm.y);
        float u[8];
        if (pu < 64) {
#pragma unroll
            for (int m = i + 1; m < 8; ++m) u[m] = readlane_f(sv[B + m].x, pu);
        } else {
#pragma unroll
            for (int m = i + 1; m < 8; ++m) u[m] = readlane_f(sv[B + m].y, pu - 64);
        }
#pragma unroll
        for (int m = i + 1; m < 8; ++m)
            sv[B + m] = __builtin_elementwise_fma((v2f){-u[m], -u[m]}, lm, sv[B + m]);
        if (l == 0) { keysF[8 * g + i] = key; pivsF[8 * g + i] = piv; }
    }
    __builtin_amdgcn_s_setprio(0);
    const unsigned long long b0 = __ballot(elim0 && !e0in);
    const unsigned long long b1 = __ballot(elim1 && !e1in);
    if (l == 0) masks[g] = make_ulonglong2(b0, b1);
}

__device__ __forceinline__ void decode_p(const unsigned* keysR, int (&p)[8]) {
    const uint4 ka = *(const uint4*)&keysR[0];
    const uint4 kb = *(const uint4*)&keysR[4];
    p[0] = __builtin_amdgcn_readfirstlane((int)(ka.x & 127u));
    p[1] = __builtin_amdgcn_readfirstlane((int)(ka.y & 127u));
    p[2] = __builtin_amdgcn_readfirstlane((int)(ka.z & 127u));
    p[3] = __builtin_amdgcn_readfirstlane((int)(ka.w & 127u));
    p[4] = __builtin_amdgcn_readfirstlane((int)(kb.x & 127u));
    p[5] = __builtin_amdgcn_readfirstlane((int)(kb.y & 127u));
    p[6] = __builtin_amdgcn_readfirstlane((int)(kb.z & 127u));
    p[7] = __builtin_amdgcn_readfirstlane((int)(kb.w & 127u));
}

// apply 8 pivots to all 16 cols: per pivot one uniform branch, 16 batched
// readlanes (16-wide ILP on the readlane->fma chain), then 16 pk_fma.
__device__ __forceinline__ void apply16(v2f (&sv)[16], const int (&p)[8],
                                        const float2 (&la)[8]) {
#pragma unroll
    for (int i = 0; i < 8; ++i) {
        const v2f lm = (v2f){la[i].x, la[i].y};
        float u[16];
        if (p[i] < 64) {
#pragma unroll
            for (int j = 0; j < 16; ++j) u[j] = readlane_f(sv[j].x, p[i]);
        } else {
#pragma unroll
            for (int j = 0; j < 16; ++j) u[j] = readlane_f(sv[j].y, p[i] - 64);
        }
#pragma unroll
        for (int j = 0; j < 16; ++j)
            sv[j] = __builtin_elementwise_fma((v2f){-u[j], -u[j]}, lm, sv[j]);
    }
}

// apply 8 pivots to cols sv[8..15] only (chunk A already eliminated)
__device__ __forceinline__ void apply8hi(v2f (&sv)[16], const int (&p)[8],
                                         const float2 (&la)[8]) {
#pragma unroll
    for (int i = 0; i < 8; ++i) {
        const v2f lm = (v2f){la[i].x, la[i].y};
        float u[8];
        if (p[i] < 64) {
#pragma unroll
            for (int j = 0; j < 8; ++j) u[j] = readlane_f(sv[8 + j].x, p[i]);
        } else {
#pragma unroll
            for (int j = 0; j < 8; ++j) u[j] = readlane_f(sv[8 + j].y, p[i] - 64);
        }
#pragma unroll
        for (int j = 0; j < 8; ++j)
            sv[8 + j] = __builtin_elementwise_fma((v2f){-u[j], -u[j]}, lm, sv[8 + j]);
    }
}

__global__ __launch_bounds__(NT, 8)   // 8 waves/EU = 4 blocks/CU
void slater_logdet(const float* __restrict__ rs,
                   const float* __restrict__ kpts,
                   const float* __restrict__ csw,
                   const float* __restrict__ ssw,
                   float* __restrict__ out) {
    __shared__ float2 colv[2][8][64];      // pre-multiplied, pre-zeroed pairs
    __shared__ unsigned keysF[NM];         // write-once pivot keys per step
    __shared__ float    pivsF[NM];         // write-once exact pivots
    __shared__ ulonglong2 masks[NM / 8];   // per-group new-pivot row ballots
    __shared__ float    redf[2];

    const int t  = threadIdx.x;
    const int b  = blockIdx.x;
    const int w  = t >> 6;    // wave id; owns groups w and 15-w
    const int l  = t & 63;
    const int r0 = l, r1 = l + 64;

    v2f sv[16];   // sv[j<8] = (rows r0,r1) at col 8w+j ; sv[j>=8] = col 8*(15-w)+(j-8)
    {
        const float x0 = rs[(b * NM + r0) * 3 + 0];
        const float y0 = rs[(b * NM + r0) * 3 + 1];
        const float z0 = rs[(b * NM + r0) * 3 + 2];
        const float x1 = rs[(b * NM + r1) * 3 + 0];
        const float y1 = rs[(b * NM + r1) * 3 + 1];
        const float z1 = rs[(b * NM + r1) * 3 + 2];
#pragma unroll
        for (int j = 0; j < 16; ++j) {
            const int m = (j < 8) ? (8 * w + j) : (8 * (15 - w) + (j - 8));
            const float kx = kpts[m * 3 + 0], ky = kpts[m * 3 + 1], kz = kpts[m * 3 + 2];
            const float cw = csw[m], sw = ssw[m];
            float sn, cn;
            __sincosf(kx * x0 + ky * y0 + kz * z0, &sn, &cn);
            sv[j].x = cw * cn - sw * sn;
            __sincosf(kx * x1 + ky * y1 + kz * z1, &sn, &cn);
            sv[j].y = cw * cn - sw * sn;
        }
    }

    bool elim0 = false, elim1 = false;

    // ---- bootstrap: wave 0 factors & publishes group 0 (its chunk A) ----
    if (w == 0)
        lookahead8<0>(sv, elim0, elim1, r0, r1, l, 0, colv[0], keysF, pivsF, masks);
    __syncthreads();

    // ---- main loop: 15 rounds; round rd applies group rd.
    // Wave w: chunk A (sv[0..7], group w) applied for rd < w, factored during
    //   round w-1. Chunk B (sv[8..15], group 15-w) applied for rd <= 14-w,
    //   factored during round 14-w (publishing group rd+1). Wave retires after
    //   round 14-w (wave 7 first). Pivot order identical to the (w,w+8)
    //   pairing -> bit-identical output; only ownership/balance changed.
    const int liveEnd = 14 - w;
    int rd = 0;
    for (; rd <= liveEnd; ++rd) {
        const ulonglong2 mk = masks[rd];
        elim0 = elim0 || (((mk.x >> l) & 1ull) != 0);
        elim1 = elim1 || (((mk.y >> l) & 1ull) != 0);

        int p[8];
        decode_p(&keysF[8 * rd], p);
        const float2 (*cp)[64] = colv[rd & 1];
        float2 la[8];
#pragma unroll
        for (int i = 0; i < 8; ++i) la[i] = cp[i][l];   // 1 lgkm wait, not 8

        if (rd < w) apply16(sv, p, la);   // both chunks live
        else        apply8hi(sv, p, la);  // chunk A retired (or retiring now)

        if (rd == w - 1)     // factor chunk A (group w == rd+1)
            lookahead8<0>(sv, elim0, elim1, r0, r1, l, rd + 1,
                          colv[(rd + 1) & 1], keysF, pivsF, masks);
        if (rd == liveEnd && w != 0 + 0 ? (rd == 14 - w) : (rd == 14))  // see below
            ;
        if (rd == 14 - w)    // factor chunk B (group 15-w == rd+1); retire after
            lookahead8<8>(sv, elim0, elim1, r0, r1, l, rd + 1,
                          colv[(rd + 1) & 1], keysF, pivsF, masks);

        __syncthreads();
    }
    for (; rd < 15; ++rd) __syncthreads();   // retired waves: barrier-only

    // ---- log|det| = sum log|piv_k| over the write-once pivsF array ----
    float lg = 0.0f;
    if (t < NM) {
        lg = __logf(fabsf(pivsF[t]));
#pragma unroll
        for (int off = 32; off > 0; off >>= 1)
            lg += __shfl_xor(lg, off, 64);
        if ((t & 63) == 0) redf[t >> 6] = lg;
    }
    __syncthreads();
    if (t == 0) out[b] = redf[0] + redf[1];
}

extern "C" void kernel_launch(void* const* d_in, const int* in_sizes, int n_in,
                              void* d_out, int out_size, void* d_ws, size_t ws_size,
                              hipStream_t stream) {
    const float* rs = (const float*)d_in[0];
    const float* kp = (const float*)d_in[1];
    const float* cs = (const float*)d_in[2];
    const float* ss = (const float*)d_in[3];
    float* out = (float*)d_out;
    const int batch = in_sizes[0] / (NM * 3);  // 4096
    slater_logdet<<<dim3(batch), dim3(NT), 0, stream>>>(rs, kp, cs, ss, out);
}

// Round 3
// 413.984 us; speedup vs baseline: 1.1042x; 1.0228x over previous
//
#include <hip/hip_runtime.h>
#include <stdint.h>

#define NM 128    // matrix dim / electrons
#define NT 1024   // 16 waves; wave w owns ONE group of 8 cols: 8w..8w+7.
                  // lane l owns rows l, l+64. 16 rounds of 8 pivots.
                  // sv[8] = 16 VGPRs -> fits 64-VGPR budget (8 waves/EU,
                  // 2 blocks/CU = 32 waves/CU) with NO scratch spills.

typedef float v2f __attribute__((ext_vector_type(2)));

__device__ __forceinline__ float readlane_f(float v, int lane) {
    return __int_as_float(__builtin_amdgcn_readlane(__float_as_int(v), lane));
}

// Full 64-lane unsigned max via DPP (VALU pipe); result valid in lane 63.
__device__ __forceinline__ unsigned wave_max_dpp(unsigned x) {
    int v = (int)x;
#define DPP_STEP(ctrl) \
    { int o = __builtin_amdgcn_update_dpp(0, v, ctrl, 0xf, 0xf, true); \
      v = ((unsigned)o > (unsigned)v) ? o : v; }
    DPP_STEP(0x111)  // row_shr:1
    DPP_STEP(0x112)  // row_shr:2
    DPP_STEP(0x114)  // row_shr:4
    DPP_STEP(0x118)  // row_shr:8
    DPP_STEP(0x142)  // row_bcast:15
    DPP_STEP(0x143)  // row_bcast:31
#undef DPP_STEP
    return (unsigned)v;
}

__device__ __forceinline__ unsigned pack_key(float v, int r) {
    // monotone in |v|; drop 6 mantissa LSBs to make room for the 7-bit row id
    return (((__float_as_uint(v) & 0x7fffffffu) >> 6) << 7) | (unsigned)r;
}

// max(ka,kb) over the wave, broadcast to all lanes (uniform result)
__device__ __forceinline__ unsigned argmax_bcast(unsigned ka, unsigned kb) {
    const unsigned m = wave_max_dpp(ka > kb ? ka : kb);
    return (unsigned)__builtin_amdgcn_readlane((int)m, 63);
}

// read pivot row p's element of a (row r0, row r1) register pair; p uniform
__device__ __forceinline__ float sel_readlane(v2f c, int p) {
    return (p < 64) ? readlane_f(c.x, p) : readlane_f(c.y, p - 64);
}

// Factor this wave's 8 columns (group g) in place, publishing pre-multiplied
// + pre-zeroed multipliers, keys, exact pivots, elim ballots. Extractions
// batched: one uniform branch per pivot, contiguous readlanes, then pk_fma.
__device__ __forceinline__ void factor8(v2f (&sv)[8], bool& elim0, bool& elim1,
                                        int r0, int r1, int l, int g,
                                        float2 (*colvg)[64],
                                        unsigned* keysF, float* pivsF,
                                        ulonglong2* masks) {
    const bool e0in = elim0, e1in = elim1;
    __builtin_amdgcn_s_setprio(1);   // convoy-critical wave: favor its issue
#pragma unroll
    for (int i = 0; i < 8; ++i) {
        const v2f c = sv[i];
        const unsigned key = argmax_bcast(elim0 ? 0u : pack_key(c.x, r0),
                                          elim1 ? 0u : pack_key(c.y, r1));
        const int pu = __builtin_amdgcn_readfirstlane((int)(key & 127u));
        const float piv = sel_readlane(c, pu);
        const float rcp = __builtin_amdgcn_rcpf(piv);
        elim0 = elim0 || (r0 == pu);
        elim1 = elim1 || (r1 == pu);
        const v2f lm = { elim0 ? 0.0f : c.x * rcp,
                         elim1 ? 0.0f : c.y * rcp };
        colvg[i][l] = make_float2(lm.x, lm.y);
        float u[8];
        if (pu < 64) {
#pragma unroll
            for (int m = i + 1; m < 8; ++m) u[m] = readlane_f(sv[m].x, pu);
        } else {
#pragma unroll
            for (int m = i + 1; m < 8; ++m) u[m] = readlane_f(sv[m].y, pu - 64);
        }
#pragma unroll
        for (int m = i + 1; m < 8; ++m)
            sv[m] = __builtin_elementwise_fma((v2f){-u[m], -u[m]}, lm, sv[m]);
        if (l == 0) { keysF[8 * g + i] = key; pivsF[8 * g + i] = piv; }
    }
    __builtin_amdgcn_s_setprio(0);
    const unsigned long long b0 = __ballot(elim0 && !e0in);
    const unsigned long long b1 = __ballot(elim1 && !e1in);
    if (l == 0) masks[g] = make_ulonglong2(b0, b1);
}

__device__ __forceinline__ void decode_p(const unsigned* keysR, int (&p)[8]) {
    const uint4 ka = *(const uint4*)&keysR[0];
    const uint4 kb = *(const uint4*)&keysR[4];
    p[0] = __builtin_amdgcn_readfirstlane((int)(ka.x & 127u));
    p[1] = __builtin_amdgcn_readfirstlane((int)(ka.y & 127u));
    p[2] = __builtin_amdgcn_readfirstlane((int)(ka.z & 127u));
    p[3] = __builtin_amdgcn_readfirstlane((int)(ka.w & 127u));
    p[4] = __builtin_amdgcn_readfirstlane((int)(kb.x & 127u));
    p[5] = __builtin_amdgcn_readfirstlane((int)(kb.y & 127u));
    p[6] = __builtin_amdgcn_readfirstlane((int)(kb.z & 127u));
    p[7] = __builtin_amdgcn_readfirstlane((int)(kb.w & 127u));
}

__global__ __launch_bounds__(NT, 8)   // 8 waves/EU = 2 blocks/CU (32 waves/CU)
void slater_logdet(const float* __restrict__ rs,
                   const float* __restrict__ kpts,
                   const float* __restrict__ csw,
                   const float* __restrict__ ssw,
                   float* __restrict__ out) {
    __shared__ float2 colv[2][8][64];      // double-buffered multiplier panels
    __shared__ unsigned keysF[NM];         // write-once pivot keys per step
    __shared__ float    pivsF[NM];         // write-once exact pivots
    __shared__ ulonglong2 masks[NM / 8];   // per-group new-pivot row ballots
    __shared__ float    redf[2];

    const int t  = threadIdx.x;
    const int b  = blockIdx.x;
    const int w  = t >> 6;    // wave id 0..15; owns cols 8w..8w+7
    const int l  = t & 63;
    const int r0 = l, r1 = l + 64;

    v2f sv[8];   // sv[j] = (rows r0,r1) at col 8w+j
    {
        const float x0 = rs[(b * NM + r0) * 3 + 0];
        const float y0 = rs[(b * NM + r0) * 3 + 1];
        const float z0 = rs[(b * NM + r0) * 3 + 2];
        const float x1 = rs[(b * NM + r1) * 3 + 0];
        const float y1 = rs[(b * NM + r1) * 3 + 1];
        const float z1 = rs[(b * NM + r1) * 3 + 2];
#pragma unroll
        for (int j = 0; j < 8; ++j) {
            const int m = 8 * w + j;
            const float kx = kpts[m * 3 + 0], ky = kpts[m * 3 + 1], kz = kpts[m * 3 + 2];
            const float cw = csw[m], sw = ssw[m];
            float sn, cn;
            __sincosf(kx * x0 + ky * y0 + kz * z0, &sn, &cn);
            sv[j].x = cw * cn - sw * sn;
            __sincosf(kx * x1 + ky * y1 + kz * z1, &sn, &cn);
            sv[j].y = cw * cn - sw * sn;
        }
    }

    bool elim0 = false, elim1 = false;

    // ---- bootstrap: wave 0 factors & publishes group 0 ----
    if (w == 0)
        factor8(sv, elim0, elim1, r0, r1, l, 0, colv[0], keysF, pivsF, masks);
    __syncthreads();

    // ---- main loop: 15 rounds; round rd applies group rd's 8 pivots to all
    //      later groups (waves w > rd), then wave rd+1 factors group rd+1
    //      into the other colv buffer. Pivot order and per-column update
    //      order identical to the 512-thread schedule -> bit-identical output.
    for (int rd = 0; rd < 15; ++rd) {
        if (w > rd) {
            const ulonglong2 mk = masks[rd];
            elim0 = elim0 || (((mk.x >> l) & 1ull) != 0);
            elim1 = elim1 || (((mk.y >> l) & 1ull) != 0);

            int p[8];
            decode_p(&keysF[8 * rd], p);
            const float2 (*cp)[64] = colv[rd & 1];
#pragma unroll
            for (int i = 0; i < 8; ++i) {
                const float2 la = cp[i][l];          // JIT ds_read_b64
                const v2f lm = (v2f){la.x, la.y};
                float u[8];
                if (p[i] < 64) {
#pragma unroll
                    for (int j = 0; j < 8; ++j) u[j] = readlane_f(sv[j].x, p[i]);
                } else {
#pragma unroll
                    for (int j = 0; j < 8; ++j) u[j] = readlane_f(sv[j].y, p[i] - 64);
                }
#pragma unroll
                for (int j = 0; j < 8; ++j)
                    sv[j] = __builtin_elementwise_fma((v2f){-u[j], -u[j]}, lm, sv[j]);
            }

            if (w == rd + 1)   // factor own group; this wave then retires
                factor8(sv, elim0, elim1, r0, r1, l, rd + 1,
                        colv[(rd + 1) & 1], keysF, pivsF, masks);
        }
        __syncthreads();
    }

    // ---- log|det| = sum log|piv_k| over the write-once pivsF array ----
    float lg = 0.0f;
    if (t < NM) {
        lg = __logf(fabsf(pivsF[t]));
#pragma unroll
        for (int off = 32; off > 0; off >>= 1)
            lg += __shfl_xor(lg, off, 64);
        if ((t & 63) == 0) redf[t >> 6] = lg;
    }
    __syncthreads();
    if (t == 0) out[b] = redf[0] + redf[1];
}

extern "C" void kernel_launch(void* const* d_in, const int* in_sizes, int n_in,
                              void* d_out, int out_size, void* d_ws, size_t ws_size,
                              hipStream_t stream) {
    const float* rs = (const float*)d_in[0];
    const float* kp = (const float*)d_in[1];
    const float* cs = (const float*)d_in[2];
    const float* ss = (const float*)d_in[3];
    float* out = (float*)d_out;
    const int batch = in_sizes[0] / (NM * 3);  // 4096
    slater_logdet<<<dim3(batch), dim3(NT), 0, stream>>>(rs, kp, cs, ss, out);
}

// Round 4
// 413.968 us; speedup vs baseline: 1.1043x; 1.0000x over previous
//
#include <hip/hip_runtime.h>
#include <stdint.h>

#define NM 128    // matrix dim / electrons
#define NT 1024   // 16 waves; wave w owns group w (cols 8w..8w+7).
                  // lane l owns rows l, l+64.
                  // NO round barriers: producer-consumer via LDS flag pipeline.

typedef float v2f __attribute__((ext_vector_type(2)));

__device__ __forceinline__ float readlane_f(float v, int lane) {
    return __int_as_float(__builtin_amdgcn_readlane(__float_as_int(v), lane));
}

// Full 64-lane unsigned max via DPP (VALU pipe); result valid in lane 63.
__device__ __forceinline__ unsigned wave_max_dpp(unsigned x) {
    int v = (int)x;
#define DPP_STEP(ctrl) \
    { int o = __builtin_amdgcn_update_dpp(0, v, ctrl, 0xf, 0xf, true); \
      v = ((unsigned)o > (unsigned)v) ? o : v; }
    DPP_STEP(0x111)  // row_shr:1
    DPP_STEP(0x112)  // row_shr:2
    DPP_STEP(0x114)  // row_shr:4
    DPP_STEP(0x118)  // row_shr:8
    DPP_STEP(0x142)  // row_bcast:15
    DPP_STEP(0x143)  // row_bcast:31
#undef DPP_STEP
    return (unsigned)v;
}

__device__ __forceinline__ unsigned pack_key(float v, int r) {
    // monotone in |v|; drop 6 mantissa LSBs to make room for the 7-bit row id
    return (((__float_as_uint(v) & 0x7fffffffu) >> 6) << 7) | (unsigned)r;
}

// max(ka,kb) over the wave, broadcast to all lanes (uniform result)
__device__ __forceinline__ unsigned argmax_bcast(unsigned ka, unsigned kb) {
    const unsigned m = wave_max_dpp(ka > kb ? ka : kb);
    return (unsigned)__builtin_amdgcn_readlane((int)m, 63);
}

// read pivot row p's element of a (row r0, row r1) register pair; p uniform
__device__ __forceinline__ float sel_readlane(v2f c, int p) {
    return (p < 64) ? readlane_f(c.x, p) : readlane_f(c.y, p - 64);
}

// Factor this wave's 8 columns (group g) in place, publishing pre-multiplied
// + pre-zeroed multipliers, keys, exact pivots, elim ballots.
__device__ __forceinline__ void factor8(v2f (&sv)[8], bool& elim0, bool& elim1,
                                        int r0, int r1, int l, int g,
                                        float2 (*colvg)[64],
                                        unsigned* keysF, float* pivsF,
                                        ulonglong2* masks) {
    const bool e0in = elim0, e1in = elim1;
    __builtin_amdgcn_s_setprio(1);   // frontier-critical wave: favor its issue
#pragma unroll
    for (int i = 0; i < 8; ++i) {
        const v2f c = sv[i];
        const unsigned key = argmax_bcast(elim0 ? 0u : pack_key(c.x, r0),
                                          elim1 ? 0u : pack_key(c.y, r1));
        const int pu = __builtin_amdgcn_readfirstlane((int)(key & 127u));
        const float piv = sel_readlane(c, pu);
        const float rcp = __builtin_amdgcn_rcpf(piv);
        elim0 = elim0 || (r0 == pu);
        elim1 = elim1 || (r1 == pu);
        const v2f lm = { elim0 ? 0.0f : c.x * rcp,
                         elim1 ? 0.0f : c.y * rcp };
        colvg[i][l] = make_float2(lm.x, lm.y);
        float u[8];
        if (pu < 64) {
#pragma unroll
            for (int m = i + 1; m < 8; ++m) u[m] = readlane_f(sv[m].x, pu);
        } else {
#pragma unroll
            for (int m = i + 1; m < 8; ++m) u[m] = readlane_f(sv[m].y, pu - 64);
        }
#pragma unroll
        for (int m = i + 1; m < 8; ++m)
            sv[m] = __builtin_elementwise_fma((v2f){-u[m], -u[m]}, lm, sv[m]);
        if (l == 0) { keysF[8 * g + i] = key; pivsF[8 * g + i] = piv; }
    }
    __builtin_amdgcn_s_setprio(0);
    const unsigned long long b0 = __ballot(elim0 && !e0in);
    const unsigned long long b1 = __ballot(elim1 && !e1in);
    if (l == 0) masks[g] = make_ulonglong2(b0, b1);
}

__device__ __forceinline__ void decode_p(const unsigned* keysR, int (&p)[8]) {
    const uint4 ka = *(const uint4*)&keysR[0];
    const uint4 kb = *(const uint4*)&keysR[4];
    p[0] = __builtin_amdgcn_readfirstlane((int)(ka.x & 127u));
    p[1] = __builtin_amdgcn_readfirstlane((int)(ka.y & 127u));
    p[2] = __builtin_amdgcn_readfirstlane((int)(ka.z & 127u));
    p[3] = __builtin_amdgcn_readfirstlane((int)(ka.w & 127u));
    p[4] = __builtin_amdgcn_readfirstlane((int)(kb.x & 127u));
    p[5] = __builtin_amdgcn_readfirstlane((int)(kb.y & 127u));
    p[6] = __builtin_amdgcn_readfirstlane((int)(kb.z & 127u));
    p[7] = __builtin_amdgcn_readfirstlane((int)(kb.w & 127u));
}

__global__ __launch_bounds__(NT, 8)   // 8 waves/EU = 2 blocks/CU (32 waves/CU)
void slater_logdet(const float* __restrict__ rs,
                   const float* __restrict__ kpts,
                   const float* __restrict__ csw,
                   const float* __restrict__ ssw,
                   float* __restrict__ out) {
    // 15 panels: group 15's multipliers are never consumed; its factor writes
    // go to panel 0, which is dead by then (every wave applies group 0 before
    // its own factor, and all 15 prior factors precede wave 15's in the flag
    // chain). Keeps static LDS at 62.9 KB (< 64 KB), 2 blocks/CU.
    __shared__ float2 colv[15][8][64];     // per-group multiplier panels
    __shared__ unsigned keysF[NM];         // write-once pivot keys per step
    __shared__ float    pivsF[NM];         // write-once exact pivots
    __shared__ ulonglong2 masks[16];       // per-group new-pivot row ballots
    __shared__ float    redf[2];
    __shared__ int      gcount;            // groups published (monotone 0..16)

    const int t  = threadIdx.x;
    const int b  = blockIdx.x;
    const int w  = t >> 6;    // wave id 0..15; owns cols 8w..8w+7
    const int l  = t & 63;
    const int r0 = l, r1 = l + 64;

    v2f sv[8];   // sv[j] = (rows r0,r1) at col 8w+j
    {
        const float x0 = rs[(b * NM + r0) * 3 + 0];
        const float y0 = rs[(b * NM + r0) * 3 + 1];
        const float z0 = rs[(b * NM + r0) * 3 + 2];
        const float x1 = rs[(b * NM + r1) * 3 + 0];
        const float y1 = rs[(b * NM + r1) * 3 + 1];
        const float z1 = rs[(b * NM + r1) * 3 + 2];
#pragma unroll
        for (int j = 0; j < 8; ++j) {
            const int m = 8 * w + j;
            const float kx = kpts[m * 3 + 0], ky = kpts[m * 3 + 1], kz = kpts[m * 3 + 2];
            const float cw = csw[m], sw = ssw[m];
            float sn, cn;
            __sincosf(kx * x0 + ky * y0 + kz * z0, &sn, &cn);
            sv[j].x = cw * cn - sw * sn;
            __sincosf(kx * x1 + ky * y1 + kz * z1, &sn, &cn);
            sv[j].y = cw * cn - sw * sn;
        }
    }

    if (t == 0) gcount = 0;
    __syncthreads();   // publishes gcount=0; only barrier before the tail

    bool elim0 = false, elim1 = false;

    // ---- flag-pipelined elimination: apply each published group in order,
    //      then factor own group and publish. Pivot order and per-column
    //      update order identical to the barrier schedule -> bit-identical.
    int applied = 0;
    while (applied < w) {
        const int avail = __hip_atomic_load(&gcount, __ATOMIC_ACQUIRE,
                                            __HIP_MEMORY_SCOPE_WORKGROUP);
        const int lim = avail < w ? avail : w;
        if (lim > applied) {
            do {
                const int g = applied;
                const ulonglong2 mk = masks[g];
                elim0 = elim0 || (((mk.x >> l) & 1ull) != 0);
                elim1 = elim1 || (((mk.y >> l) & 1ull) != 0);
                int p[8];
                decode_p(&keysF[8 * g], p);
                float2 la[8];
#pragma unroll
                for (int i = 0; i < 8; ++i) la[i] = colv[g][i][l];  // 1 lgkm wait
#pragma unroll
                for (int i = 0; i < 8; ++i) {
                    const v2f lm = (v2f){la[i].x, la[i].y};
                    float u[8];
                    if (p[i] < 64) {
#pragma unroll
                        for (int j = 0; j < 8; ++j) u[j] = readlane_f(sv[j].x, p[i]);
                    } else {
#pragma unroll
                        for (int j = 0; j < 8; ++j) u[j] = readlane_f(sv[j].y, p[i] - 64);
                    }
#pragma unroll
                    for (int j = 0; j < 8; ++j)
                        sv[j] = __builtin_elementwise_fma((v2f){-u[j], -u[j]}, lm, sv[j]);
                }
                ++applied;
            } while (applied < lim);
        } else if (w - avail > 1) {
            __builtin_amdgcn_s_sleep(1);   // far from our turn: stay quiet
        }                                   // 1 away: tight-poll the handoff
    }

    factor8(sv, elim0, elim1, r0, r1, l, w,
            colv[w < 15 ? w : 0], keysF, pivsF, masks);
    __hip_atomic_store(&gcount, w + 1, __ATOMIC_RELEASE,
                       __HIP_MEMORY_SCOPE_WORKGROUP);   // all lanes store same value

    __syncthreads();   // all 16 groups published; pivsF complete

    // ---- log|det| = sum log|piv_k| over the write-once pivsF array ----
    float lg = 0.0f;
    if (t < NM) {
        lg = __logf(fabsf(pivsF[t]));
#pragma unroll
        for (int off = 32; off > 0; off >>= 1)
            lg += __shfl_xor(lg, off, 64);
        if ((t & 63) == 0) redf[t >> 6] = lg;
    }
    __syncthreads();
    if (t == 0) out[b] = redf[0] + redf[1];
}

extern "C" void kernel_launch(void* const* d_in, const int* in_sizes, int n_in,
                              void* d_out, int out_size, void* d_ws, size_t ws_size,
                              hipStream_t stream) {
    const float* rs = (const float*)d_in[0];
    const float* kp = (const float*)d_in[1];
    const float* cs = (const float*)d_in[2];
    const float* ss = (const float*)d_in[3];
    float* out = (float*)d_out;
    const int batch = in_sizes[0] / (NM * 3);  // 4096
    slater_logdet<<<dim3(batch), dim3(NT), 0, stream>>>(rs, kp, cs, ss, out);
}